// Round 2
// baseline (30.326 us; speedup 1.0000x reference)
//
#include <hip/hip_runtime.h>

// LIF neuron scan: v' = v*0.5 + x + r; s = (v'>0); v = s ? 0 : v'
// T=100 sequential steps, B*N = 131072 independent chains.
// Memory-bound streaming: read 105 MB, write 52 MB per call.
//
// Mapping: one thread per element chain (scalar) -> 131072 threads =
// 512 blocks x 256 = 8 waves/CU (2 waves/SIMD), 2x the latency hiding of
// the float2 mapping. Loads stay fully coalesced (64 lanes x 4 B = 256 B
// per instruction). Output stored non-temporally: it is written once and
// never read, so keep it from evicting L3-resident inputs.

#define TAU 0.5f

__global__ __launch_bounds__(256) void lif_scan_kernel(
    const float* __restrict__ inp,
    const float* __restrict__ rec,
    float* __restrict__ out,
    int n,    // elements per timestep (B*N)
    int T)
{
    const int i = blockIdx.x * blockDim.x + threadIdx.x;
    if (i >= n) return;

    float v = 0.0f;

    #pragma unroll 10
    for (int t = 0; t < T; ++t) {
        const size_t off = (size_t)t * (size_t)n + (size_t)i;
        const float x = inp[off];
        const float r = rec[off];

        // Only multiply is by 0.5 (exact) -> fp-contract cannot change the
        // rounded result vs numpy's (v*0.5 + x) + r, so the >0 test is
        // bit-identical to the reference.
        v = v * TAU + x + r;

        const float s = (v > 0.0f) ? 1.0f : 0.0f;
        v = (v > 0.0f) ? 0.0f : v;

        __builtin_nontemporal_store(s, &out[off]);
    }
}

extern "C" void kernel_launch(void* const* d_in, const int* in_sizes, int n_in,
                              void* d_out, int out_size, void* d_ws, size_t ws_size,
                              hipStream_t stream) {
    const float* inp = (const float*)d_in[0];
    const float* rec = (const float*)d_in[1];
    float* out = (float*)d_out;

    const int T = 100;
    const int n = in_sizes[0] / T;       // B*N = 131072 element chains

    const int block = 256;
    const int grid = (n + block - 1) / block;   // 512 blocks -> 2 per CU

    lif_scan_kernel<<<grid, block, 0, stream>>>(inp, rec, out, n, T);
}

// Round 3
// 28.945 us; speedup vs baseline: 1.0477x; 1.0477x over previous
//
#include <hip/hip_runtime.h>

// LIF neuron scan: v' = v*0.5 + x + r; s = (v'>0); v = s ? 0 : v'
// T=100 sequential steps, B*N = 131072 independent chains.
//
// Mapping: float2 per thread (8 B/lane loads), 65536 threads = 256 blocks
// x 256 = 4 waves/CU — R0's proven config (28.1 us vs 30.3 for scalar).
// New: explicit software pipeline. Chunks of CH=5 timesteps; while chunk c
// is computed+stored, chunk c+1's 10 loads (5 KB/wave) are already in
// flight -> ~20 KB/CU outstanding continuously, no vmcnt drain bubble at
// unroll boundaries. All buffer indices are compile-time (full unroll) so
// everything stays in registers.

#define TAU 0.5f
#define CH 5

__global__ __launch_bounds__(256) void lif_scan_kernel(
    const float2* __restrict__ inp,
    const float2* __restrict__ rec,
    float2* __restrict__ out,
    int n2,   // float2 lanes per timestep (B*N/2) = 65536
    int T)    // 100
{
    const int i = blockIdx.x * blockDim.x + threadIdx.x;
    if (i >= n2) return;

    float vx = 0.0f, vy = 0.0f;

    float2 xb[CH], rb[CH];

    // prologue: load chunk 0
    #pragma unroll
    for (int k = 0; k < CH; ++k) {
        xb[k] = inp[(size_t)k * n2 + i];
        rb[k] = rec[(size_t)k * n2 + i];
    }

    const int nchunks = T / CH;   // 20

    for (int c = 0; c < nchunks - 1; ++c) {
        float2 xn[CH], rn[CH];
        const size_t nb = (size_t)(c + 1) * CH * n2 + i;

        // issue next chunk's loads before touching this chunk's data
        #pragma unroll
        for (int k = 0; k < CH; ++k) {
            xn[k] = inp[nb + (size_t)k * n2];
            rn[k] = rec[nb + (size_t)k * n2];
        }

        const size_t ob = (size_t)c * CH * n2 + i;
        #pragma unroll
        for (int k = 0; k < CH; ++k) {
            // v*0.5 is exact (pow2), so fma contraction can't change the
            // rounded result vs numpy's (v*0.5 + x) + r -> spike test exact.
            vx = vx * TAU + xb[k].x + rb[k].x;
            vy = vy * TAU + xb[k].y + rb[k].y;

            float2 s;
            s.x = (vx > 0.0f) ? 1.0f : 0.0f;
            s.y = (vy > 0.0f) ? 1.0f : 0.0f;
            vx = (vx > 0.0f) ? 0.0f : vx;
            vy = (vy > 0.0f) ? 0.0f : vy;

            out[ob + (size_t)k * n2] = s;

            xb[k] = xn[k];
            rb[k] = rn[k];
        }
    }

    // epilogue: last chunk (no prefetch)
    {
        const int c = nchunks - 1;
        const size_t ob = (size_t)c * CH * n2 + i;
        #pragma unroll
        for (int k = 0; k < CH; ++k) {
            vx = vx * TAU + xb[k].x + rb[k].x;
            vy = vy * TAU + xb[k].y + rb[k].y;

            float2 s;
            s.x = (vx > 0.0f) ? 1.0f : 0.0f;
            s.y = (vy > 0.0f) ? 1.0f : 0.0f;
            vx = (vx > 0.0f) ? 0.0f : vx;
            vy = (vy > 0.0f) ? 0.0f : vy;

            out[ob + (size_t)k * n2] = s;
        }
    }
}

extern "C" void kernel_launch(void* const* d_in, const int* in_sizes, int n_in,
                              void* d_out, int out_size, void* d_ws, size_t ws_size,
                              hipStream_t stream) {
    const float* inp = (const float*)d_in[0];
    const float* rec = (const float*)d_in[1];
    float* out = (float*)d_out;

    const int T = 100;
    const int per_t = in_sizes[0] / T;   // B*N = 131072
    const int n2 = per_t / 2;            // 65536 float2 lanes

    const int block = 256;
    const int grid = (n2 + block - 1) / block;   // 256 blocks -> 1 per CU

    lif_scan_kernel<<<grid, block, 0, stream>>>(
        (const float2*)inp, (const float2*)rec, (float2*)out, n2, T);
}